// Round 17
// baseline (177.526 us; speedup 1.0000x reference)
//
#include <hip/hip_runtime.h>

// VQ-VAE quantization, round 17: 32x32x16 MFMA prefilter + exact fp32 rescore.
// One body = 32 codes x 32 points = 4 chained mfma_f32_32x32x16_bf16
// (2x FLOP/instr vs 16x16x32) -> ~1.4 inst/code vs r16's 3.75.
// Block = 32 points (grid 2048), 4 waves x 1024 codes; regs ~120 -> 4 waves/SIMD.
// C/D map (m74/m101): col=lane&31, row=(reg&3)+8*(reg>>2)+4*(lane>>5).
// A/B maps by the same partition: A row=lane&31, B col=lane&31, k=(lane>>5)*8+e.
// Sampled threshold (4 tiles/wave -> block-wide 512 codes) - DELTA=0.25;
// ctz push; exact fp32 rescore + LDS atomicMin((ordbits(dist)<<32)|code)
// -> exact argmin, first-index ties (jnp.argmin semantics).

#define NPTS    65536
#define CDIM    64
#define KCODES  4096
#define WAVES   4
#define PPB     32                  // points per block
#define KPW     (KCODES / WAVES)    // 1024 codes per wave
#define TILES   (KPW / 32)          // 32 tiles of 32 codes
#define PADC    64                  // pad codes (prefetch overrun target)
#define LISTCAP 4096
#define DELTA   0.25f

typedef __attribute__((ext_vector_type(8))) short short8;
typedef __attribute__((ext_vector_type(16))) float f32x16;

__device__ __forceinline__ unsigned short f2bf(float x) {
    unsigned u = __float_as_uint(x);
    return (unsigned short)((u + 0x7FFFu + ((u >> 16) & 1u)) >> 16);  // RNE
}

struct BT { short8 b[4]; float hh; };

// cb fp32 -> bf16 copy + h[k] = 0.5*||e_k||^2
__global__ __launch_bounds__(256) void vq_prep(const float* __restrict__ cb,
                                               short* __restrict__ cbb,
                                               float* __restrict__ h) {
    int k = blockIdx.x * 256 + threadIdx.x;
    const float4* p = reinterpret_cast<const float4*>(cb + (size_t)k * CDIM);
    float s0 = 0.f, s1 = 0.f, s2 = 0.f, s3 = 0.f;
#pragma unroll
    for (int i = 0; i < 16; i += 2) {
        float4 va = p[i], vb = p[i + 1];
        s0 = fmaf(va.x, va.x, s0); s1 = fmaf(va.y, va.y, s1);
        s2 = fmaf(va.z, va.z, s2); s3 = fmaf(va.w, va.w, s3);
        s0 = fmaf(vb.x, vb.x, s0); s1 = fmaf(vb.y, vb.y, s1);
        s2 = fmaf(vb.z, vb.z, s2); s3 = fmaf(vb.w, vb.w, s3);
        short8 o;
        o[0] = (short)f2bf(va.x); o[1] = (short)f2bf(va.y);
        o[2] = (short)f2bf(va.z); o[3] = (short)f2bf(va.w);
        o[4] = (short)f2bf(vb.x); o[5] = (short)f2bf(vb.y);
        o[6] = (short)f2bf(vb.z); o[7] = (short)f2bf(vb.w);
        *reinterpret_cast<short8*>(cbb + (size_t)k * CDIM + i * 4) = o;
    }
    h[k] = 0.5f * ((s0 + s1) + (s2 + s3));
}

__global__ __launch_bounds__(256) void vq_main(const float* __restrict__ enc,
                                               const float* __restrict__ cbf,
                                               const short* __restrict__ cbb,
                                               const float* __restrict__ h,
                                               float* __restrict__ out) {
    __shared__ unsigned list[LISTCAP];
    __shared__ float rowmax[WAVES][PPB];
    __shared__ float thrL[PPB];
    __shared__ unsigned long long mkey[PPB];
    __shared__ unsigned lcnt;

    const int tid  = threadIdx.x;
    const int wid  = tid >> 6, lane = tid & 63;
    const int col  = lane & 31, hs = lane >> 5;
    const int pbase = blockIdx.x * PPB;    // 32 points per block
    const int k0 = wid * KPW;              // this wave's 1024-code slice

    if (tid == 0) lcnt = 0;
    if (tid < PPB) mkey[tid] = ~0ull;

    // ---- A fragments: the block's 32 points as bf16 ----
    // 32x32x16 A: row = lane&31, k = (lane>>5)*8 + e; chunk c covers k = c*16..+16
    short8 afr[4];
#pragma unroll
    for (int c = 0; c < 4; ++c) {
        const float4* xp = reinterpret_cast<const float4*>(
            enc + (size_t)(pbase + col) * CDIM + c * 16 + hs * 8);
        float4 v0 = xp[0], v1 = xp[1];
        short8 a;
        a[0] = (short)f2bf(v0.x); a[1] = (short)f2bf(v0.y);
        a[2] = (short)f2bf(v0.z); a[3] = (short)f2bf(v0.w);
        a[4] = (short)f2bf(v1.x); a[5] = (short)f2bf(v1.y);
        a[6] = (short)f2bf(v1.z); a[7] = (short)f2bf(v1.w);
        afr[c] = a;
    }
    __syncthreads();   // lcnt/mkey init visible before any push

    // B tile: 32 codes x 64 dims; lane reads code k0+t*32+col, chunk c at
    // dims c*16 + hs*8 (16B each, stride 32B). +1 h load.
    auto loadB = [&](int t, BT& s) {
        int code = k0 + t * 32 + col;      // may run past KCODES (pad-backed)
        const short* base = cbb + (size_t)code * CDIM + hs * 8;
#pragma unroll
        for (int c = 0; c < 4; ++c)
            s.b[c] = *reinterpret_cast<const short8*>(base + c * 16);
        s.hh = h[code];
    };

    // 4 chained MFMAs over K=64; C-in = cin (not aliased to D)
    auto mfmaT = [&](const BT& s, const f32x16& cin) -> f32x16 {
        f32x16 acc = __builtin_amdgcn_mfma_f32_32x32x16_bf16(afr[0], s.b[0], cin, 0, 0, 0);
        acc = __builtin_amdgcn_mfma_f32_32x32x16_bf16(afr[1], s.b[1], acc, 0, 0, 0);
        acc = __builtin_amdgcn_mfma_f32_32x32x16_bf16(afr[2], s.b[2], acc, 0, 0, 0);
        acc = __builtin_amdgcn_mfma_f32_32x32x16_bf16(afr[3], s.b[3], acc, 0, 0, 0);
        return acc;
    };

    // ---- sample sweep: tiles {0,8,16,24}, row max only ----
    float best[16];
#pragma unroll
    for (int r = 0; r < 16; ++r) best[r] = -__builtin_inff();

    {
        BT s0, s1;
        loadB(0, s0); loadB(8, s1);
        {
            f32x16 ci; float nh = -s0.hh;
#pragma unroll
            for (int r = 0; r < 16; ++r) ci[r] = nh;
            f32x16 acc = mfmaT(s0, ci);
            loadB(16, s0);
#pragma unroll
            for (int r = 0; r < 16; ++r) best[r] = fmaxf(best[r], acc[r]);
        }
        {
            f32x16 ci; float nh = -s1.hh;
#pragma unroll
            for (int r = 0; r < 16; ++r) ci[r] = nh;
            f32x16 acc = mfmaT(s1, ci);
            loadB(24, s1);
#pragma unroll
            for (int r = 0; r < 16; ++r) best[r] = fmaxf(best[r], acc[r]);
        }
        {
            f32x16 ci; float nh = -s0.hh;
#pragma unroll
            for (int r = 0; r < 16; ++r) ci[r] = nh;
            f32x16 acc = mfmaT(s0, ci);
#pragma unroll
            for (int r = 0; r < 16; ++r) best[r] = fmaxf(best[r], acc[r]);
        }
        {
            f32x16 ci; float nh = -s1.hh;
#pragma unroll
            for (int r = 0; r < 16; ++r) ci[r] = nh;
            f32x16 acc = mfmaT(s1, ci);
#pragma unroll
            for (int r = 0; r < 16; ++r) best[r] = fmaxf(best[r], acc[r]);
        }
    }

    // reduce max over the 32 col-lanes (xor 1..16 stays within the hs group)
#pragma unroll
    for (int m = 1; m <= 16; m <<= 1)
#pragma unroll
        for (int r = 0; r < 16; ++r)
            best[r] = fmaxf(best[r], __shfl_xor(best[r], m, 64));
    if (col == 0) {   // lanes 0 (hs=0) and 32 (hs=1) cover all 32 rows
#pragma unroll
        for (int r = 0; r < 16; ++r)
            rowmax[wid][(r & 3) + 8 * (r >> 2) + 4 * hs] = best[r];
    }
    __syncthreads();
    if (tid < PPB) {  // cross-wave max of sampled maxes -> threshold
        float m0 = fmaxf(rowmax[0][tid], rowmax[1][tid]);
        float m1 = fmaxf(rowmax[2][tid], rowmax[3][tid]);
        thrL[tid] = fmaxf(m0, m1) - DELTA;
    }
    __syncthreads();

    // mthr = -thr per C/D reg slot, persistent MFMA C-in
    f32x16 mthr;
#pragma unroll
    for (int r = 0; r < 16; ++r)
        mthr[r] = -thrL[(r & 3) + 8 * (r >> 2) + 4 * hs];

    // ---- main sweep: 32 tiles; C-in = mthr; test acc >= h; ctz push ----
    {
        BT s0, s1;
        loadB(0, s0); loadB(1, s1);
#define S2BODY(SLOT, T)                                                        \
        {                                                                      \
            f32x16 acc = mfmaT(SLOT, mthr);                                    \
            float hh = SLOT.hh;                                                \
            loadB((T) + 2, SLOT);   /* affine; pad-backed past TILES */        \
            unsigned mask = 0u;                                                \
            _Pragma("unroll")                                                  \
            for (int r = 0; r < 16; ++r)                                       \
                mask |= (acc[r] >= hh) ? (1u << r) : 0u;                       \
            if (mask) {                                                        \
                unsigned code = (unsigned)(k0 + (T) * 32 + col);               \
                do {                                                           \
                    int kz = __builtin_ctz(mask);                              \
                    mask &= mask - 1u;                                         \
                    unsigned row = (unsigned)((kz & 3) + 8 * (kz >> 2) + 4 * hs); \
                    unsigned pos = atomicAdd(&lcnt, 1u);                       \
                    if (pos < LISTCAP) list[pos] = (row << 12) | code;         \
                } while (mask);                                                \
            }                                                                  \
        }
        for (int t = 0; t < TILES; t += 2) {
            S2BODY(s0, t + 0)
            S2BODY(s1, t + 1)
        }
#undef S2BODY
    }
    __syncthreads();

    // ---- exact fp32 rescore: 4 lanes per candidate (coalesced 256B) ----
    unsigned cnt = lcnt; if (cnt > LISTCAP) cnt = LISTCAP;
    for (unsigned t4 = tid; t4 < cnt * 4; t4 += 256) {
        unsigned t = t4 >> 2; int q = t4 & 3;
        unsigned e = list[t];
        int row = (int)(e >> 12), c = (int)(e & 4095u);
        const float4* xp = reinterpret_cast<const float4*>(enc + (size_t)(pbase + row) * CDIM) + q * 4;
        const float4* ep = reinterpret_cast<const float4*>(cbf + (size_t)c * CDIM) + q * 4;
        float a0 = 0.f, a1 = 0.f, a2 = 0.f, a3 = 0.f;
#pragma unroll
        for (int i = 0; i < 4; ++i) {
            float4 xv = xp[i], ev = ep[i];
            a0 = fmaf(xv.x, ev.x, a0); a1 = fmaf(xv.y, ev.y, a1);
            a2 = fmaf(xv.z, ev.z, a2); a3 = fmaf(xv.w, ev.w, a3);
        }
        float p = (a0 + a1) + (a2 + a3);
        p += __shfl_xor(p, 1, 64);
        p += __shfl_xor(p, 2, 64);               // full dot in all 4 lanes
        if (q == 0) {
            float d2 = fmaf(-2.f, p, 2.f * h[c]);     // esq - 2*dot (bit-identical everywhere)
            unsigned bb = __float_as_uint(d2);
            unsigned ord = bb ^ (unsigned)(((int)bb >> 31) | 0x80000000);  // monotonic
            atomicMin(&mkey[row], ((unsigned long long)ord << 32) | (unsigned)c);
        }
    }
    __syncthreads();

    // ---- finalize: gather winner rows (8 threads per point) + idx ----
    {
        int p = tid >> 3, q = tid & 7;
        int c = (int)(mkey[p] & 4095u);
        const float4* ep = reinterpret_cast<const float4*>(cbf + (size_t)c * CDIM);
        float4* op = reinterpret_cast<float4*>(out + (size_t)(pbase + p) * CDIM);
        op[q] = ep[q];
        op[q + 8] = ep[q + 8];
        if (tid < PPB)
            out[(size_t)NPTS * CDIM + pbase + tid] = (float)(mkey[tid] & 4095u);
    }
}

extern "C" void kernel_launch(void* const* d_in, const int* in_sizes, int n_in,
                              void* d_out, int out_size, void* d_ws, size_t ws_size,
                              hipStream_t stream) {
    const float* enc = (const float*)d_in[0];
    const float* cb  = (const float*)d_in[1];
    float* out = (float*)d_out;

    // ws: cbb bf16[(4096+64)*64] (520KB) | h fp32[4096+64]
    short* cbb = (short*)d_ws;
    float* hws = (float*)(cbb + (size_t)(KCODES + PADC) * CDIM);

    vq_prep<<<KCODES / 256, 256, 0, stream>>>(cb, cbb, hws);
    vq_main<<<NPTS / PPB, 256, 0, stream>>>(enc, cb, cbb, hws, out);
}

// Round 18
// 129.305 us; speedup vs baseline: 1.3729x; 1.3729x over previous
//
#include <hip/hip_runtime.h>

// VQ-VAE quantization, round 18: r16 (134us) with h moved off the VMEM queue.
//  - hlds[4160] staged to LDS once per block -> per-body VMEM ops 3 -> 2
//    (homogeneous b0/b1 pair, shared address math); rescore h reads also LDS.
//  - BT slot loses its float; LISTCAP 4096 keeps LDS ~34.5KB (4 blocks/CU).
// Carried from r16: persistent mthr MFMA C-in (no per-tile acc init), affine
// pad-backed prefetch depth 4, sign-mask + ctz push, sampled threshold
// (8/64 tiles/wave + cross-wave max) - DELTA=0.25 (>= 2x worst bf16 dot err,
// provably winner-preserving), exact fp32 rescore + LDS atomicMin
// ((ordbits(dist)<<32)|code) -> exact argmin, first-index ties.

#define NPTS    65536
#define CDIM    64
#define KCODES  4096
#define WAVES   4
#define KPW     (KCODES / WAVES)   // 1024 codes per wave
#define TILES   (KPW / 16)         // 64 tiles of 16 codes
#define PADC    64                 // pad codes (prefetch overrun target)
#define LISTCAP 4096
#define DELTA   0.25f

typedef __attribute__((ext_vector_type(8))) short short8;
typedef __attribute__((ext_vector_type(4))) float f32x4;

__device__ __forceinline__ unsigned short f2bf(float x) {
    unsigned u = __float_as_uint(x);
    return (unsigned short)((u + 0x7FFFu + ((u >> 16) & 1u)) >> 16);  // RNE
}

struct BT { short8 b0, b1; };

// cb fp32 -> bf16 copy + h[k] = 0.5*||e_k||^2
__global__ __launch_bounds__(256) void vq_prep(const float* __restrict__ cb,
                                               short* __restrict__ cbb,
                                               float* __restrict__ h) {
    int k = blockIdx.x * 256 + threadIdx.x;
    const float4* p = reinterpret_cast<const float4*>(cb + (size_t)k * CDIM);
    float s0 = 0.f, s1 = 0.f, s2 = 0.f, s3 = 0.f;
#pragma unroll
    for (int i = 0; i < 16; i += 2) {
        float4 va = p[i], vb = p[i + 1];
        s0 = fmaf(va.x, va.x, s0); s1 = fmaf(va.y, va.y, s1);
        s2 = fmaf(va.z, va.z, s2); s3 = fmaf(va.w, va.w, s3);
        s0 = fmaf(vb.x, vb.x, s0); s1 = fmaf(vb.y, vb.y, s1);
        s2 = fmaf(vb.z, vb.z, s2); s3 = fmaf(vb.w, vb.w, s3);
        short8 o;
        o[0] = (short)f2bf(va.x); o[1] = (short)f2bf(va.y);
        o[2] = (short)f2bf(va.z); o[3] = (short)f2bf(va.w);
        o[4] = (short)f2bf(vb.x); o[5] = (short)f2bf(vb.y);
        o[6] = (short)f2bf(vb.z); o[7] = (short)f2bf(vb.w);
        *reinterpret_cast<short8*>(cbb + (size_t)k * CDIM + i * 4) = o;
    }
    h[k] = 0.5f * ((s0 + s1) + (s2 + s3));
}

__global__ __launch_bounds__(256) void vq_main(const float* __restrict__ enc,
                                               const float* __restrict__ cbf,
                                               const short* __restrict__ cbb,
                                               const float* __restrict__ h,
                                               float* __restrict__ out) {
    __shared__ unsigned list[LISTCAP];
    __shared__ float hlds[KCODES + PADC];
    __shared__ float rowmax[WAVES][64];
    __shared__ float thrL[64];
    __shared__ unsigned long long mkey[64];
    __shared__ unsigned lcnt;

    const int tid  = threadIdx.x;
    const int wid  = tid >> 6, lane = tid & 63;
    const int lrow = lane & 15, lseg = lane >> 4;
    const int pbase = blockIdx.x * 64;     // 64 points per block
    const int k0 = wid * KPW;              // this wave's 1024-code slice

    if (tid == 0) lcnt = 0;
    if (tid < 64) mkey[tid] = ~0ull;
    // stage h (incl. pad; pad values unused by any computed body)
    for (int i = tid; i < KCODES + PADC; i += 256) hlds[i] = h[i];

    // ---- A fragments: the block's 64 points as bf16 ----
    // 16x16x32 A layout: row = lane&15, k = (lane>>4)*8 + e (+32 per kk)
    short8 afr[4][2];
#pragma unroll
    for (int rt = 0; rt < 4; ++rt)
#pragma unroll
        for (int kk = 0; kk < 2; ++kk) {
            const float4* xp = reinterpret_cast<const float4*>(
                enc + (size_t)(pbase + rt * 16 + lrow) * CDIM + kk * 32 + lseg * 8);
            float4 v0 = xp[0], v1 = xp[1];
            short8 a;
            a[0] = (short)f2bf(v0.x); a[1] = (short)f2bf(v0.y);
            a[2] = (short)f2bf(v0.z); a[3] = (short)f2bf(v0.w);
            a[4] = (short)f2bf(v1.x); a[5] = (short)f2bf(v1.y);
            a[6] = (short)f2bf(v1.z); a[7] = (short)f2bf(v1.w);
            afr[rt][kk] = a;
        }
    __syncthreads();   // hlds + lcnt/mkey visible

    auto loadB = [&](int ct, BT& s) {
        int code = k0 + ct * 16 + lrow;    // may run PADC past KCODES (pad-backed)
        const short* base = cbb + (size_t)code * CDIM + lseg * 8;
        s.b0 = *reinterpret_cast<const short8*>(base);
        s.b1 = *reinterpret_cast<const short8*>(base + 32);
    };

    // ---- sample sweep: tiles {0,8,...,56}, row max only ----
    f32x4 best[4];
#pragma unroll
    for (int rt = 0; rt < 4; ++rt)
#pragma unroll
        for (int i = 0; i < 4; ++i) best[rt][i] = -__builtin_inff();

    {
        BT s0, s1, s2, s3;
        loadB(0, s0); loadB(8, s1); loadB(16, s2); loadB(24, s3);
#define SSBODY(SLOT, J)                                                        \
        {                                                                      \
            float nh = -hlds[k0 + (J) * 128 + lrow];                           \
            f32x4 acc[4];                                                      \
            _Pragma("unroll")                                                  \
            for (int rt = 0; rt < 4; ++rt) {                                   \
                acc[rt][0] = nh; acc[rt][1] = nh;                              \
                acc[rt][2] = nh; acc[rt][3] = nh;                              \
            }                                                                  \
            _Pragma("unroll")                                                  \
            for (int rt = 0; rt < 4; ++rt)                                     \
                acc[rt] = __builtin_amdgcn_mfma_f32_16x16x32_bf16(afr[rt][0], SLOT.b0, acc[rt], 0, 0, 0); \
            _Pragma("unroll")                                                  \
            for (int rt = 0; rt < 4; ++rt)                                     \
                acc[rt] = __builtin_amdgcn_mfma_f32_16x16x32_bf16(afr[rt][1], SLOT.b1, acc[rt], 0, 0, 0); \
            _Pragma("unroll")                                                  \
            for (int rt = 0; rt < 4; ++rt)                                     \
                _Pragma("unroll")                                              \
                for (int i = 0; i < 4; ++i)                                    \
                    best[rt][i] = fmaxf(best[rt][i], acc[rt][i]);              \
            loadB((((J) + 4) & 7) * 8, SLOT);                                  \
        }
        SSBODY(s0, 0) SSBODY(s1, 1) SSBODY(s2, 2) SSBODY(s3, 3)
        SSBODY(s0, 4) SSBODY(s1, 5) SSBODY(s2, 6) SSBODY(s3, 7)
#undef SSBODY
    }

    // intra-wave max over the 16 col-lanes
#pragma unroll
    for (int m = 1; m <= 8; m <<= 1)
#pragma unroll
        for (int rt = 0; rt < 4; ++rt)
#pragma unroll
            for (int i = 0; i < 4; ++i)
                best[rt][i] = fmaxf(best[rt][i], __shfl_xor(best[rt][i], m, 64));
    if (lrow == 0) {   // lanes 0,16,32,48 cover all 64 rows
#pragma unroll
        for (int rt = 0; rt < 4; ++rt)
#pragma unroll
            for (int i = 0; i < 4; ++i)
                rowmax[wid][rt * 16 + lseg * 4 + i] = best[rt][i];
    }
    __syncthreads();
    if (tid < 64) {    // cross-wave max of sampled maxes -> threshold
        float m0 = fmaxf(rowmax[0][tid], rowmax[1][tid]);
        float m1 = fmaxf(rowmax[2][tid], rowmax[3][tid]);
        thrL[tid] = fmaxf(m0, m1) - DELTA;
    }
    __syncthreads();

    // mthr = -thr, persistent MFMA C-in for the whole sweep
    f32x4 mthr[4];
#pragma unroll
    for (int rt = 0; rt < 4; ++rt)
#pragma unroll
        for (int i = 0; i < 4; ++i) mthr[rt][i] = -thrL[rt * 16 + lseg * 4 + i];

    // ---- sweep 2: C-in = mthr; hh from LDS; test acc >= hh; ctz push ----
    {
        BT s0, s1, s2, s3;
        loadB(0, s0); loadB(1, s1); loadB(2, s2); loadB(3, s3);
#define S2BODY(SLOT, T)                                                        \
        {                                                                      \
            float hh = hlds[k0 + (T) * 16 + lrow];                             \
            f32x4 acc[4];                                                      \
            _Pragma("unroll")                                                  \
            for (int rt = 0; rt < 4; ++rt)                                     \
                acc[rt] = __builtin_amdgcn_mfma_f32_16x16x32_bf16(afr[rt][0], SLOT.b0, mthr[rt], 0, 0, 0); \
            _Pragma("unroll")                                                  \
            for (int rt = 0; rt < 4; ++rt)                                     \
                acc[rt] = __builtin_amdgcn_mfma_f32_16x16x32_bf16(afr[rt][1], SLOT.b1, acc[rt], 0, 0, 0); \
            unsigned mask = 0u;                                                \
            _Pragma("unroll")                                                  \
            for (int rt = 0; rt < 4; ++rt)                                     \
                _Pragma("unroll")                                              \
                for (int i = 0; i < 4; ++i)                                    \
                    mask |= (acc[rt][i] >= hh) ? (1u << (rt * 4 + i)) : 0u;    \
            if (mask) {                                                        \
                unsigned code = (unsigned)(k0 + (T) * 16 + lrow);              \
                do {                                                           \
                    int kz = __builtin_ctz(mask);                              \
                    mask &= mask - 1u;                                         \
                    unsigned row = ((unsigned)(kz >> 2) << 4)                  \
                                 + (unsigned)(lseg * 4) + (unsigned)(kz & 3);  /* C/D map (m89) */ \
                    unsigned pos = atomicAdd(&lcnt, 1u);                       \
                    if (pos < LISTCAP) list[pos] = (row << 12) | code;         \
                } while (mask);                                                \
            }                                                                  \
            loadB((T) + 4, SLOT);   /* affine; pad-backed past TILES */        \
        }
        for (int t = 0; t < TILES; t += 4) {
            S2BODY(s0, t + 0)
            S2BODY(s1, t + 1)
            S2BODY(s2, t + 2)
            S2BODY(s3, t + 3)
        }
#undef S2BODY
    }
    __syncthreads();

    // ---- exact fp32 rescore: 4 lanes per candidate (coalesced 256B) ----
    unsigned cnt = lcnt; if (cnt > LISTCAP) cnt = LISTCAP;
    for (unsigned t4 = tid; t4 < cnt * 4; t4 += 256) {
        unsigned t = t4 >> 2; int q = t4 & 3;
        unsigned e = list[t];
        int row = (int)(e >> 12), c = (int)(e & 4095u);
        const float4* xp = reinterpret_cast<const float4*>(enc + (size_t)(pbase + row) * CDIM) + q * 4;
        const float4* ep = reinterpret_cast<const float4*>(cbf + (size_t)c * CDIM) + q * 4;
        float a0 = 0.f, a1 = 0.f, a2 = 0.f, a3 = 0.f;
#pragma unroll
        for (int i = 0; i < 4; ++i) {
            float4 xv = xp[i], ev = ep[i];
            a0 = fmaf(xv.x, ev.x, a0); a1 = fmaf(xv.y, ev.y, a1);
            a2 = fmaf(xv.z, ev.z, a2); a3 = fmaf(xv.w, ev.w, a3);
        }
        float p = (a0 + a1) + (a2 + a3);
        p += __shfl_xor(p, 1, 64);
        p += __shfl_xor(p, 2, 64);               // full dot in all 4 lanes
        if (q == 0) {
            float d2 = fmaf(-2.f, p, 2.f * hlds[c]);  // esq - 2*dot (bit-identical everywhere)
            unsigned bb = __float_as_uint(d2);
            unsigned ord = bb ^ (unsigned)(((int)bb >> 31) | 0x80000000);  // monotonic
            atomicMin(&mkey[row], ((unsigned long long)ord << 32) | (unsigned)c);
        }
    }
    __syncthreads();

    // ---- finalize: gather winner rows (4 threads per point) + idx ----
    {
        int p = tid >> 2, q = tid & 3;
        int c = (int)(mkey[p] & 4095u);
        const float4* ep = reinterpret_cast<const float4*>(cbf + (size_t)c * CDIM) + q * 4;
        float4* op = reinterpret_cast<float4*>(out + (size_t)(pbase + p) * CDIM) + q * 4;
#pragma unroll
        for (int i = 0; i < 4; ++i) op[i] = ep[i];
        if (tid < 64)
            out[(size_t)NPTS * CDIM + pbase + tid] = (float)(mkey[tid] & 4095u);
    }
}

extern "C" void kernel_launch(void* const* d_in, const int* in_sizes, int n_in,
                              void* d_out, int out_size, void* d_ws, size_t ws_size,
                              hipStream_t stream) {
    const float* enc = (const float*)d_in[0];
    const float* cb  = (const float*)d_in[1];
    float* out = (float*)d_out;

    // ws: cbb bf16[(4096+64)*64] (520KB) | h fp32[4096+64]
    short* cbb = (short*)d_ws;
    float* hws = (float*)(cbb + (size_t)(KCODES + PADC) * CDIM);

    vq_prep<<<KCODES / 256, 256, 0, stream>>>(cb, cbb, hws);
    vq_main<<<NPTS / 64, 256, 0, stream>>>(enc, cb, cbb, hws, out);
}